// Round 1
// 1007.849 us; speedup vs baseline: 1.0172x; 1.0172x over previous
//
#include <hip/hip_runtime.h>
#include <math.h>

#define N_TOK  131072
#define DIM    1024
#define HIDN   256
#define ATTN   128
#define NSEG   64
#define SEGLEN 2048
#define NCLS   2
#define EPSLN  1e-5f

typedef __attribute__((ext_vector_type(8))) short  short8;
typedef __attribute__((ext_vector_type(4))) float  f32x4;

__device__ __forceinline__ unsigned short f2bf(float f) {
    unsigned int u = __float_as_uint(f);
    u += 0x7fffu + ((u >> 16) & 1u);
    return (unsigned short)(u >> 16);
}
__device__ __forceinline__ float bf2f(unsigned short h) {
    return __uint_as_float(((unsigned int)h) << 16);
}
__device__ __forceinline__ float gelu_exact(float x) {
    return 0.5f * x * (1.0f + erff(x * 0.70710678118654752f));
}

// out[C][R] (bf16) = transpose(in[R][C] fp32)
__global__ __launch_bounds__(256) void transpose_cvt(const float* __restrict__ in,
                                                     unsigned short* __restrict__ out,
                                                     int R, int C) {
    __shared__ float t[32][33];
    const int bx = blockIdx.x * 32;   // along C
    const int by = blockIdx.y * 32;   // along R
    const int x = threadIdx.x, y = threadIdx.y;  // 32 x 8
#pragma unroll
    for (int i = 0; i < 32; i += 8) {
        int r = by + y + i, c = bx + x;
        if (r < R && c < C) t[y + i][x] = in[(size_t)r * C + c];
    }
    __syncthreads();
#pragma unroll
    for (int i = 0; i < 32; i += 8) {
        int c = bx + y + i, r = by + x;
        if (c < C && r < R) out[(size_t)c * R + r] = f2bf(t[x][y + i]);
    }
}

__global__ void build_bvu(const float* __restrict__ bv, const float* __restrict__ bu,
                          float* __restrict__ bvu) {
    int t = threadIdx.x;
    bvu[t] = (t < 128) ? bv[t] : bu[t - 128];
}

// Fused GEMM: C[M x 256] = A[M x K] @ Wt^T + bias, then per-row epilogue.
// Wt is [256][K] bf16 (n-major, k contiguous).
// BM=64, BN=256 (full width), BK=32. 256 threads = 4 waves; wave w owns cols [64w,64w+64).
// MFMA 16x16x32 bf16: D[row=(lane>>4)*4+r][col=lane&15] per 16x16 tile.
// MODE 0: LayerNorm(gamma g, beta be) + exact GELU -> bf16 Hout.  (row stats over 256 cols)
// MODE 1: attention score: a[row] = sum_j tanh(v_j)*sigmoid(u_j)*Ww[j] + bw,
//         where v = cols 0..127 (waves 0,1), u = cols 128..255 (waves 2,3). -> fp32 Aout.
template <int K, int MODE, bool AF32>
__global__ __launch_bounds__(256) void gemm_fused(const void* __restrict__ Aptr,
                                                  const unsigned short* __restrict__ Wt,
                                                  const float* __restrict__ bias,
                                                  const float* __restrict__ g,
                                                  const float* __restrict__ be,
                                                  unsigned short* __restrict__ Hout,
                                                  const float* __restrict__ Ww,
                                                  const float* __restrict__ bw,
                                                  float* __restrict__ Aout) {
    // staging: As 64x40 ushort (5120 B) + Ws 256x40 ushort (20480 B) = 25600 B.
    // MODE 0 epilogue aliases 2 KB over staging (dead after the post-loop barrier).
    // MODE 1 epilogue aliases us[64][129] f32 (33024 B) + pw[2][64] (512 B) = 33536 B.
    constexpr int SMEM_BYTES = (MODE == 1) ? 33536 : 25600;
    __shared__ __align__(16) char smem[SMEM_BYTES];
    auto As = (unsigned short (*)[40])(smem);
    auto Ws = (unsigned short (*)[40])(smem + 5120);

    const int tid  = threadIdx.x;
    const int wave = tid >> 6, lane = tid & 63;
    const int lr = lane & 15, lq = lane >> 4;
    const int srow = tid >> 2, skq = (tid & 3) * 8;
    const size_t row0 = (size_t)blockIdx.x * 64;

    f32x4 acc[4][4];
#pragma unroll
    for (int i = 0; i < 4; i++)
#pragma unroll
        for (int j = 0; j < 4; j++) acc[i][j] = (f32x4)0.0f;

    for (int k0 = 0; k0 < K; k0 += 32) {
        short8 aw;
        if constexpr (AF32) {
            const float* A = (const float*)Aptr;
            const float* p = &A[(row0 + srow) * K + k0 + skq];
            float4 v0 = *(const float4*)p;
            float4 v1 = *(const float4*)(p + 4);
            aw[0] = (short)f2bf(v0.x); aw[1] = (short)f2bf(v0.y);
            aw[2] = (short)f2bf(v0.z); aw[3] = (short)f2bf(v0.w);
            aw[4] = (short)f2bf(v1.x); aw[5] = (short)f2bf(v1.y);
            aw[6] = (short)f2bf(v1.z); aw[7] = (short)f2bf(v1.w);
        } else {
            const unsigned short* A = (const unsigned short*)Aptr;
            aw = *(const short8*)&A[(row0 + srow) * K + k0 + skq];
        }
        short8 ww[4];
#pragma unroll
        for (int c = 0; c < 4; c++)
            ww[c] = *(const short8*)&Wt[(size_t)(srow + 64 * c) * K + k0 + skq];

        __syncthreads();   // previous tile fully consumed
        *(short8*)&As[srow][skq] = aw;
#pragma unroll
        for (int c = 0; c < 4; c++)
            *(short8*)&Ws[srow + 64 * c][skq] = ww[c];
        __syncthreads();

        short8 a[4], b[4];
#pragma unroll
        for (int i = 0; i < 4; i++) a[i] = *(const short8*)&As[16 * i + lr][lq * 8];
#pragma unroll
        for (int j = 0; j < 4; j++) b[j] = *(const short8*)&Ws[64 * wave + 16 * j + lr][lq * 8];
#pragma unroll
        for (int i = 0; i < 4; i++)
#pragma unroll
            for (int j = 0; j < 4; j++)
                acc[i][j] = __builtin_amdgcn_mfma_f32_16x16x32_bf16(a[i], b[j], acc[i][j], 0, 0, 0);
    }

    __syncthreads();   // all waves' final ds_reads done -> safe to alias staging LDS

    // add bias in place: element (i,j,r) is at row 16i+4lq+r, col 64*wave+16j+lr
    float bjv[4];
#pragma unroll
    for (int j = 0; j < 4; j++) bjv[j] = bias[wave * 64 + 16 * j + lr];
#pragma unroll
    for (int i = 0; i < 4; i++)
#pragma unroll
        for (int j = 0; j < 4; j++)
#pragma unroll
            for (int r = 0; r < 4; r++) acc[i][j][r] += bjv[j];

    if constexpr (MODE == 0) {
        // ---- fused LayerNorm + GELU -> bf16 ----
        float (*red)[4][64] = (float (*)[4][64])smem;   // [2][wave][row]: sum, sumsq
#pragma unroll
        for (int i = 0; i < 4; i++)
#pragma unroll
            for (int r = 0; r < 4; r++) {
                float s = 0.0f, sq = 0.0f;
#pragma unroll
                for (int j = 0; j < 4; j++) { float v = acc[i][j][r]; s += v; sq += v * v; }
                // reduce across the 16 lanes (lr) holding the same row
#pragma unroll
                for (int m = 1; m < 16; m <<= 1) { s += __shfl_xor(s, m); sq += __shfl_xor(sq, m); }
                if (lr == 0) {
                    red[0][wave][16 * i + 4 * lq + r] = s;
                    red[1][wave][16 * i + 4 * lq + r] = sq;
                }
            }
        __syncthreads();
        float gj[4], bej[4];
#pragma unroll
        for (int j = 0; j < 4; j++) {
            gj[j]  = g[wave * 64 + 16 * j + lr];
            bej[j] = be[wave * 64 + 16 * j + lr];
        }
#pragma unroll
        for (int i = 0; i < 4; i++)
#pragma unroll
            for (int r = 0; r < 4; r++) {
                const int row = 16 * i + 4 * lq + r;
                const float s  = red[0][0][row] + red[0][1][row] + red[0][2][row] + red[0][3][row];
                const float sq = red[1][0][row] + red[1][1][row] + red[1][2][row] + red[1][3][row];
                const float mu  = s * (1.0f / HIDN);
                const float var = sq * (1.0f / HIDN) - mu * mu;
                const float rs  = rsqrtf(var + EPSLN);
#pragma unroll
                for (int j = 0; j < 4; j++) {
                    const float o = (acc[i][j][r] - mu) * rs * gj[j] + bej[j];
                    Hout[(row0 + row) * 256 + wave * 64 + 16 * j + lr] = f2bf(gelu_exact(o));
                }
            }
    } else {
        // ---- fused attention score ----
        float (*us)[129] = (float (*)[129])smem;            // sigmoid(u), padded stride
        float (*pw)[64]  = (float (*)[64])(smem + 33024);   // per-wave row partials
        if (wave >= 2) {
            const int cb = (wave - 2) * 64;
#pragma unroll
            for (int i = 0; i < 4; i++)
#pragma unroll
                for (int j = 0; j < 4; j++)
#pragma unroll
                    for (int r = 0; r < 4; r++)
                        us[16 * i + 4 * lq + r][cb + 16 * j + lr] =
                            1.0f / (1.0f + expf(-acc[i][j][r]));
        }
        __syncthreads();
        if (wave < 2) {
            const int cb = wave * 64;
            float wwj[4];
#pragma unroll
            for (int j = 0; j < 4; j++) wwj[j] = Ww[cb + 16 * j + lr];
#pragma unroll
            for (int i = 0; i < 4; i++)
#pragma unroll
                for (int r = 0; r < 4; r++) {
                    const int row = 16 * i + 4 * lq + r;
                    float s = 0.0f;
#pragma unroll
                    for (int j = 0; j < 4; j++)
                        s += tanhf(acc[i][j][r]) * us[row][cb + 16 * j + lr] * wwj[j];
#pragma unroll
                    for (int m = 1; m < 16; m <<= 1) s += __shfl_xor(s, m);
                    if (lr == 0) pw[wave][row] = s;
                }
        }
        __syncthreads();
        if (tid < 64) Aout[row0 + tid] = pw[0][tid] + pw[1][tid] + bw[0];
    }
}

// In-place softmax over each contiguous segment of 2048 scores.
__global__ __launch_bounds__(256) void seg_softmax(float* __restrict__ A) {
    __shared__ float red[256];
    const int seg = blockIdx.x, tid = threadIdx.x;
    float* a = A + (size_t)seg * SEGLEN;
    float m = -1e30f;
#pragma unroll
    for (int c = 0; c < 8; c++) m = fmaxf(m, a[tid + 256 * c]);
    red[tid] = m; __syncthreads();
    for (int s = 128; s > 0; s >>= 1) {
        if (tid < s) red[tid] = fmaxf(red[tid], red[tid + s]);
        __syncthreads();
    }
    m = red[0]; __syncthreads();
    float e[8]; float sum = 0.0f;
#pragma unroll
    for (int c = 0; c < 8; c++) { e[c] = expf(a[tid + 256 * c] - m); sum += e[c]; }
    red[tid] = sum; __syncthreads();
    for (int s = 128; s > 0; s >>= 1) {
        if (tid < s) red[tid] += red[tid + s];
        __syncthreads();
    }
    const float inv = 1.0f / red[0];
#pragma unroll
    for (int c = 0; c < 8; c++) a[tid + 256 * c] = e[c] * inv;
}

// Zp[b][col] = sum over 256 rows (b = seg*8+chunk) of attn[row]*h[row][col]
__global__ __launch_bounds__(256) void pool_partial(const float* __restrict__ Attn,
                                                    const unsigned short* __restrict__ H,
                                                    float* __restrict__ Zp) {
    __shared__ float aw[256];
    const int tid = threadIdx.x;
    const size_t rbase = (size_t)blockIdx.x * 256;
    aw[tid] = Attn[rbase + tid];
    __syncthreads();
    const unsigned short* h = H + rbase * 256 + tid;
    float acc = 0.0f;
    for (int r = 0; r < 256; r++) acc += aw[r] * bf2f(h[(size_t)r * 256]);
    Zp[rbase + tid] = acc;
}

// z = sum of 8 partials; logits = gelu(z @ Wc1 + bc1) @ Wc2 + bc2. One 256-thr block per segment.
__global__ __launch_bounds__(256) void head_kernel(const float* __restrict__ Zp,
                                                   const float* __restrict__ Wc1,
                                                   const float* __restrict__ bc1,
                                                   const float* __restrict__ Wc2,
                                                   const float* __restrict__ bc2,
                                                   float* __restrict__ Out) {
    __shared__ float zs[256];
    __shared__ float hs[128];
    __shared__ float red[4];
    const int seg = blockIdx.x, tid = threadIdx.x;
    float z = 0.0f;
#pragma unroll
    for (int c = 0; c < 8; c++) z += Zp[((size_t)seg * 8 + c) * 256 + tid];
    zs[tid] = z;
    __syncthreads();
    if (tid < 128) {
        float acc = bc1[tid];
        for (int k = 0; k < 256; k++) acc += zs[k] * Wc1[k * 128 + tid];
        hs[tid] = gelu_exact(acc);
    }
    __syncthreads();
    const int cls = tid >> 7, j = tid & 127;
    float val = hs[j] * Wc2[j * 2 + cls];
#pragma unroll
    for (int o = 32; o > 0; o >>= 1) val += __shfl_down(val, o);
    if ((tid & 63) == 0) red[tid >> 6] = val;
    __syncthreads();
    if (tid < 2) Out[seg * 2 + tid] = red[tid * 2] + red[tid * 2 + 1] + bc2[tid];
}

extern "C" void kernel_launch(void* const* d_in, const int* in_sizes, int n_in,
                              void* d_out, int out_size, void* d_ws, size_t ws_size,
                              hipStream_t stream) {
    const float* x   = (const float*)d_in[0];
    const float* W1  = (const float*)d_in[2];
    const float* b1  = (const float*)d_in[3];
    const float* g1  = (const float*)d_in[4];
    const float* be1 = (const float*)d_in[5];
    const float* W2  = (const float*)d_in[6];
    const float* b2  = (const float*)d_in[7];
    const float* g2  = (const float*)d_in[8];
    const float* be2 = (const float*)d_in[9];
    const float* Wv  = (const float*)d_in[10];
    const float* bv  = (const float*)d_in[11];
    const float* Wu  = (const float*)d_in[12];
    const float* bu  = (const float*)d_in[13];
    const float* Ww  = (const float*)d_in[14];
    const float* bw  = (const float*)d_in[15];
    const float* Wc1 = (const float*)d_in[16];
    const float* bc1 = (const float*)d_in[17];
    const float* Wc2 = (const float*)d_in[18];
    const float* bc2 = (const float*)d_in[19];
    float* out = (float*)d_out;

    char* p = (char*)d_ws;
    unsigned short* h1b    = (unsigned short*)p; p += (size_t)N_TOK * HIDN * 2;  // 67 MB
    unsigned short* h2b    = (unsigned short*)p; p += (size_t)N_TOK * HIDN * 2;  // 67 MB
    float*          scores = (float*)p;          p += (size_t)N_TOK * 4;
    unsigned short* W1t    = (unsigned short*)p; p += (size_t)HIDN * DIM * 2;
    unsigned short* W2t    = (unsigned short*)p; p += (size_t)HIDN * HIDN * 2;
    unsigned short* Wvut   = (unsigned short*)p; p += (size_t)HIDN * HIDN * 2;
    float*          bvu    = (float*)p;          p += 256 * 4;
    float*          Zp     = (float*)p;          p += (size_t)NSEG * 8 * HIDN * 4;

    dim3 tb(32, 8);
    transpose_cvt<<<dim3(HIDN / 32, DIM / 32), tb, 0, stream>>>(W1, W1t, DIM, HIDN);
    transpose_cvt<<<dim3(HIDN / 32, HIDN / 32), tb, 0, stream>>>(W2, W2t, HIDN, HIDN);
    transpose_cvt<<<dim3(ATTN / 32, HIDN / 32), tb, 0, stream>>>(Wv, Wvut, HIDN, ATTN);
    transpose_cvt<<<dim3(ATTN / 32, HIDN / 32), tb, 0, stream>>>(Wu, Wvut + (size_t)ATTN * HIDN, HIDN, ATTN);
    build_bvu<<<1, 256, 0, stream>>>(bv, bu, bvu);

    // gemm1 + LN + GELU -> h1b (bf16)
    gemm_fused<DIM, 0, true><<<N_TOK / 64, 256, 0, stream>>>(
        x, W1t, b1, g1, be1, h1b, nullptr, nullptr, nullptr);
    // gemm2 + LN + GELU -> h2b (bf16)
    gemm_fused<HIDN, 0, false><<<N_TOK / 64, 256, 0, stream>>>(
        h1b, W2t, b2, g2, be2, h2b, nullptr, nullptr, nullptr);
    // gemm3 (v|u) + tanh*sigmoid*Ww row-reduce -> scores (fp32)
    gemm_fused<HIDN, 1, false><<<N_TOK / 64, 256, 0, stream>>>(
        h2b, Wvut, bvu, nullptr, nullptr, nullptr, Ww, bw, scores);

    seg_softmax<<<NSEG, 256, 0, stream>>>(scores);
    pool_partial<<<NSEG * 8, 256, 0, stream>>>(scores, h2b, Zp);
    head_kernel<<<NSEG, 256, 0, stream>>>(Zp, Wc1, bc1, Wc2, bc2, out);
}

// Round 3
// 1007.093 us; speedup vs baseline: 1.0180x; 1.0008x over previous
//
#include <hip/hip_runtime.h>
#include <math.h>

#define N_TOK  131072
#define DIM    1024
#define HIDN   256
#define ATTN   128
#define NSEG   64
#define SEGLEN 2048
#define NCLS   2
#define EPSLN  1e-5f

typedef __attribute__((ext_vector_type(8))) short  short8;
typedef __attribute__((ext_vector_type(4))) float  f32x4;

__device__ __forceinline__ unsigned short f2bf(float f) {
    unsigned int u = __float_as_uint(f);
    u += 0x7fffu + ((u >> 16) & 1u);
    return (unsigned short)(u >> 16);
}
__device__ __forceinline__ float bf2f(unsigned short h) {
    return __uint_as_float(((unsigned int)h) << 16);
}
__device__ __forceinline__ float gelu_exact(float x) {
    return 0.5f * x * (1.0f + erff(x * 0.70710678118654752f));
}

// out[C][R] (bf16) = transpose(in[R][C] fp32)
__global__ __launch_bounds__(256) void transpose_cvt(const float* __restrict__ in,
                                                     unsigned short* __restrict__ out,
                                                     int R, int C) {
    __shared__ float t[32][33];
    const int bx = blockIdx.x * 32;   // along C
    const int by = blockIdx.y * 32;   // along R
    const int x = threadIdx.x, y = threadIdx.y;  // 32 x 8
#pragma unroll
    for (int i = 0; i < 32; i += 8) {
        int r = by + y + i, c = bx + x;
        if (r < R && c < C) t[y + i][x] = in[(size_t)r * C + c];
    }
    __syncthreads();
#pragma unroll
    for (int i = 0; i < 32; i += 8) {
        int c = bx + y + i, r = by + x;
        if (c < C && r < R) out[(size_t)c * R + r] = f2bf(t[x][y + i]);
    }
}

__global__ void build_bvu(const float* __restrict__ bv, const float* __restrict__ bu,
                          float* __restrict__ bvu) {
    int t = threadIdx.x;
    bvu[t] = (t < 128) ? bv[t] : bu[t - 128];
}

// Fused GEMM: C[M x 256] = A[M x K] @ Wt^T + bias, then per-row epilogue.
// Wt is [256][K] bf16 (n-major, k contiguous).
// BM=64, BN=256 (full width), BK=32. 256 threads = 4 waves; wave w owns cols [64w,64w+64).
// Double-buffered LDS, 2-phase software pipeline (T3 minimum recipe):
//   prologue stages tile 0; each phase {issue loads t+1 -> regs | ds_read+MFMA tile t |
//   ds_write t+1 | barrier}. One barrier per K-step (reads hit buf[cur], writes buf[cur^1]).
// MODE 0: LayerNorm(g,be) + exact GELU -> bf16 Hout.
// MODE 1: a[row] = sum_j tanh(v_j)*sigmoid(u_j)*Ww[j] + bw -> fp32 Aout.
template <int K, int MODE, bool AF32>
__global__ __launch_bounds__(256, 3) void gemm_fused(const void* __restrict__ Aptr,
                                                     const unsigned short* __restrict__ Wt,
                                                     const float* __restrict__ bias,
                                                     const float* __restrict__ g,
                                                     const float* __restrict__ be,
                                                     unsigned short* __restrict__ Hout,
                                                     const float* __restrict__ Ww,
                                                     const float* __restrict__ bw,
                                                     float* __restrict__ Aout) {
    constexpr int NT = K / 32;         // K-tiles (32 each); NT is even for K in {256,1024}
    // staging (double buffered): As 2x64x40 ushort (10240 B) + Ws 2x256x40 ushort (40960 B)
    // epilogues alias over the staging LDS after the post-loop barrier.
    __shared__ __align__(16) char smem[51200];
    auto As0 = (unsigned short (*)[40])(smem);
    auto As1 = (unsigned short (*)[40])(smem + 5120);
    auto Ws0 = (unsigned short (*)[40])(smem + 10240);
    auto Ws1 = (unsigned short (*)[40])(smem + 10240 + 20480);

    const int tid  = threadIdx.x;
    const int wave = tid >> 6, lane = tid & 63;
    const int lr = lane & 15, lq = lane >> 4;
    const int srow = tid >> 2, skq = (tid & 3) * 8;
    const size_t row0 = (size_t)blockIdx.x * 64;

    f32x4 acc[4][4];
#pragma unroll
    for (int i = 0; i < 4; i++)
#pragma unroll
        for (int j = 0; j < 4; j++) acc[i][j] = (f32x4)0.0f;

    auto loadA = [&](int k0, short8& aw) {
        if constexpr (AF32) {
            const float* A = (const float*)Aptr;
            const float* p = &A[(row0 + srow) * K + k0 + skq];
            float4 v0 = *(const float4*)p;
            float4 v1 = *(const float4*)(p + 4);
            aw[0] = (short)f2bf(v0.x); aw[1] = (short)f2bf(v0.y);
            aw[2] = (short)f2bf(v0.z); aw[3] = (short)f2bf(v0.w);
            aw[4] = (short)f2bf(v1.x); aw[5] = (short)f2bf(v1.y);
            aw[6] = (short)f2bf(v1.z); aw[7] = (short)f2bf(v1.w);
        } else {
            const unsigned short* A = (const unsigned short*)Aptr;
            aw = *(const short8*)&A[(row0 + srow) * K + k0 + skq];
        }
    };
    auto loadW = [&](int k0, short8* ww) {
#pragma unroll
        for (int c = 0; c < 4; c++)
            ww[c] = *(const short8*)&Wt[(size_t)(srow + 64 * c) * K + k0 + skq];
    };
    auto writeT = [&](unsigned short (*As)[40], unsigned short (*Ws)[40],
                      const short8& aw, const short8* ww) {
        *(short8*)&As[srow][skq] = aw;
#pragma unroll
        for (int c = 0; c < 4; c++)
            *(short8*)&Ws[srow + 64 * c][skq] = ww[c];
    };
    auto mmaT = [&](unsigned short (*As)[40], unsigned short (*Ws)[40]) {
        short8 a[4], b[4];
#pragma unroll
        for (int i = 0; i < 4; i++) a[i] = *(const short8*)&As[16 * i + lr][lq * 8];
#pragma unroll
        for (int j = 0; j < 4; j++) b[j] = *(const short8*)&Ws[64 * wave + 16 * j + lr][lq * 8];
#pragma unroll
        for (int i = 0; i < 4; i++)
#pragma unroll
            for (int j = 0; j < 4; j++)
                acc[i][j] = __builtin_amdgcn_mfma_f32_16x16x32_bf16(a[i], b[j], acc[i][j], 0, 0, 0);
    };

    short8 aw;
    short8 ww[4];
    // prologue: stage tile 0 into buf0
    loadA(0, aw);
    loadW(0, ww);
    writeT(As0, Ws0, aw, ww);
    __syncthreads();

    for (int t = 0; t < NT; t += 2) {
        // phase A: consume tile t (buf0), prefetch tile t+1 (always exists; NT even)
        loadA(32 * (t + 1), aw);
        loadW(32 * (t + 1), ww);
        mmaT(As0, Ws0);
        writeT(As1, Ws1, aw, ww);
        __syncthreads();
        // phase B: consume tile t+1 (buf1), prefetch tile t+2 if it exists
        if (t + 2 < NT) {
            loadA(32 * (t + 2), aw);
            loadW(32 * (t + 2), ww);
        }
        mmaT(As1, Ws1);
        if (t + 2 < NT) writeT(As0, Ws0, aw, ww);
        __syncthreads();   // final pass: all ds_reads drained -> safe to alias staging LDS
    }

    // add bias in place: element (i,j,r) is at row 16i+4lq+r, col 64*wave+16j+lr
    float bjv[4];
#pragma unroll
    for (int j = 0; j < 4; j++) bjv[j] = bias[wave * 64 + 16 * j + lr];
#pragma unroll
    for (int i = 0; i < 4; i++)
#pragma unroll
        for (int j = 0; j < 4; j++)
#pragma unroll
            for (int r = 0; r < 4; r++) acc[i][j][r] += bjv[j];

    if constexpr (MODE == 0) {
        // ---- fused LayerNorm + GELU -> bf16 ----
        float (*red)[4][64] = (float (*)[4][64])smem;   // [2][wave][row]: sum, sumsq
#pragma unroll
        for (int i = 0; i < 4; i++)
#pragma unroll
            for (int r = 0; r < 4; r++) {
                float s = 0.0f, sq = 0.0f;
#pragma unroll
                for (int j = 0; j < 4; j++) { float v = acc[i][j][r]; s += v; sq += v * v; }
#pragma unroll
                for (int m = 1; m < 16; m <<= 1) { s += __shfl_xor(s, m); sq += __shfl_xor(sq, m); }
                if (lr == 0) {
                    red[0][wave][16 * i + 4 * lq + r] = s;
                    red[1][wave][16 * i + 4 * lq + r] = sq;
                }
            }
        __syncthreads();
        float gj[4], bej[4];
#pragma unroll
        for (int j = 0; j < 4; j++) {
            gj[j]  = g[wave * 64 + 16 * j + lr];
            bej[j] = be[wave * 64 + 16 * j + lr];
        }
#pragma unroll
        for (int i = 0; i < 4; i++)
#pragma unroll
            for (int r = 0; r < 4; r++) {
                const int row = 16 * i + 4 * lq + r;
                const float s  = red[0][0][row] + red[0][1][row] + red[0][2][row] + red[0][3][row];
                const float sq = red[1][0][row] + red[1][1][row] + red[1][2][row] + red[1][3][row];
                const float mu  = s * (1.0f / HIDN);
                const float var = sq * (1.0f / HIDN) - mu * mu;
                const float rs  = rsqrtf(var + EPSLN);
#pragma unroll
                for (int j = 0; j < 4; j++) {
                    const float o = (acc[i][j][r] - mu) * rs * gj[j] + bej[j];
                    Hout[(row0 + row) * 256 + wave * 64 + 16 * j + lr] = f2bf(gelu_exact(o));
                }
            }
    } else {
        // ---- fused attention score ----
        float (*us)[129] = (float (*)[129])smem;            // sigmoid(u), padded stride
        float (*pw)[64]  = (float (*)[64])(smem + 33024);   // per-wave row partials
        if (wave >= 2) {
            const int cb = (wave - 2) * 64;
#pragma unroll
            for (int i = 0; i < 4; i++)
#pragma unroll
                for (int j = 0; j < 4; j++)
#pragma unroll
                    for (int r = 0; r < 4; r++)
                        us[16 * i + 4 * lq + r][cb + 16 * j + lr] =
                            1.0f / (1.0f + expf(-acc[i][j][r]));
        }
        __syncthreads();
        if (wave < 2) {
            const int cb = wave * 64;
            float wwj[4];
#pragma unroll
            for (int j = 0; j < 4; j++) wwj[j] = Ww[cb + 16 * j + lr];
#pragma unroll
            for (int i = 0; i < 4; i++)
#pragma unroll
                for (int r = 0; r < 4; r++) {
                    const int row = 16 * i + 4 * lq + r;
                    float s = 0.0f;
#pragma unroll
                    for (int j = 0; j < 4; j++)
                        s += tanhf(acc[i][j][r]) * us[row][cb + 16 * j + lr] * wwj[j];
#pragma unroll
                    for (int m = 1; m < 16; m <<= 1) s += __shfl_xor(s, m);
                    if (lr == 0) pw[wave][row] = s;
                }
        }
        __syncthreads();
        if (tid < 64) Aout[row0 + tid] = pw[0][tid] + pw[1][tid] + bw[0];
    }
}

// In-place softmax over each contiguous segment of 2048 scores.
__global__ __launch_bounds__(256) void seg_softmax(float* __restrict__ A) {
    __shared__ float red[256];
    const int seg = blockIdx.x, tid = threadIdx.x;
    float* a = A + (size_t)seg * SEGLEN;
    float m = -1e30f;
#pragma unroll
    for (int c = 0; c < 8; c++) m = fmaxf(m, a[tid + 256 * c]);
    red[tid] = m; __syncthreads();
    for (int s = 128; s > 0; s >>= 1) {
        if (tid < s) red[tid] = fmaxf(red[tid], red[tid + s]);
        __syncthreads();
    }
    m = red[0]; __syncthreads();
    float e[8]; float sum = 0.0f;
#pragma unroll
    for (int c = 0; c < 8; c++) { e[c] = expf(a[tid + 256 * c] - m); sum += e[c]; }
    red[tid] = sum; __syncthreads();
    for (int s = 128; s > 0; s >>= 1) {
        if (tid < s) red[tid] += red[tid + s];
        __syncthreads();
    }
    const float inv = 1.0f / red[0];
#pragma unroll
    for (int c = 0; c < 8; c++) a[tid + 256 * c] = e[c] * inv;
}

// Zp[b][col] = sum over 256 rows (b = seg*8+chunk) of attn[row]*h[row][col]
// Vectorized: thread (rg=tid>>5, cg=tid&31) accumulates rows [32rg,32rg+32) x cols [8cg,8cg+8)
// via short8 (16 B/lane, fully coalesced), then 8-way LDS reduction per column.
__global__ __launch_bounds__(256) void pool_partial(const float* __restrict__ Attn,
                                                    const unsigned short* __restrict__ H,
                                                    float* __restrict__ Zp) {
    __shared__ float aw[256];
    __shared__ float part[8][256];
    const int tid = threadIdx.x;
    const size_t rbase = (size_t)blockIdx.x * 256;
    aw[tid] = Attn[rbase + tid];
    __syncthreads();
    const int cg = tid & 31;
    const int rg = tid >> 5;
    float acc[8];
#pragma unroll
    for (int j = 0; j < 8; j++) acc[j] = 0.0f;
    for (int r = rg * 32; r < rg * 32 + 32; ++r) {
        short8 h8 = *(const short8*)&H[(rbase + r) * 256 + cg * 8];
        const float a = aw[r];
#pragma unroll
        for (int j = 0; j < 8; j++) acc[j] += a * bf2f((unsigned short)h8[j]);
    }
#pragma unroll
    for (int j = 0; j < 8; j++) part[rg][cg * 8 + j] = acc[j];
    __syncthreads();
    float s = 0.0f;
#pragma unroll
    for (int gq = 0; gq < 8; gq++) s += part[gq][tid];
    Zp[rbase + tid] = s;
}

// z = sum of 8 partials; logits = gelu(z @ Wc1 + bc1) @ Wc2 + bc2. One 256-thr block per segment.
__global__ __launch_bounds__(256) void head_kernel(const float* __restrict__ Zp,
                                                   const float* __restrict__ Wc1,
                                                   const float* __restrict__ bc1,
                                                   const float* __restrict__ Wc2,
                                                   const float* __restrict__ bc2,
                                                   float* __restrict__ Out) {
    __shared__ float zs[256];
    __shared__ float hs[128];
    __shared__ float red[4];
    const int seg = blockIdx.x, tid = threadIdx.x;
    float z = 0.0f;
#pragma unroll
    for (int c = 0; c < 8; c++) z += Zp[((size_t)seg * 8 + c) * 256 + tid];
    zs[tid] = z;
    __syncthreads();
    if (tid < 128) {
        float acc = bc1[tid];
        for (int k = 0; k < 256; k++) acc += zs[k] * Wc1[k * 128 + tid];
        hs[tid] = gelu_exact(acc);
    }
    __syncthreads();
    const int cls = tid >> 7, j = tid & 127;
    float val = hs[j] * Wc2[j * 2 + cls];
#pragma unroll
    for (int o = 32; o > 0; o >>= 1) val += __shfl_down(val, o);
    if ((tid & 63) == 0) red[tid >> 6] = val;
    __syncthreads();
    if (tid < 2) Out[seg * 2 + tid] = red[tid * 2] + red[tid * 2 + 1] + bc2[tid];
}

extern "C" void kernel_launch(void* const* d_in, const int* in_sizes, int n_in,
                              void* d_out, int out_size, void* d_ws, size_t ws_size,
                              hipStream_t stream) {
    const float* x   = (const float*)d_in[0];
    const float* W1  = (const float*)d_in[2];
    const float* b1  = (const float*)d_in[3];
    const float* g1  = (const float*)d_in[4];
    const float* be1 = (const float*)d_in[5];
    const float* W2  = (const float*)d_in[6];
    const float* b2  = (const float*)d_in[7];
    const float* g2  = (const float*)d_in[8];
    const float* be2 = (const float*)d_in[9];
    const float* Wv  = (const float*)d_in[10];
    const float* bv  = (const float*)d_in[11];
    const float* Wu  = (const float*)d_in[12];
    const float* bu  = (const float*)d_in[13];
    const float* Ww  = (const float*)d_in[14];
    const float* bw  = (const float*)d_in[15];
    const float* Wc1 = (const float*)d_in[16];
    const float* bc1 = (const float*)d_in[17];
    const float* Wc2 = (const float*)d_in[18];
    const float* bc2 = (const float*)d_in[19];
    float* out = (float*)d_out;

    char* p = (char*)d_ws;
    unsigned short* h1b    = (unsigned short*)p; p += (size_t)N_TOK * HIDN * 2;  // 67 MB
    unsigned short* h2b    = (unsigned short*)p; p += (size_t)N_TOK * HIDN * 2;  // 67 MB
    float*          scores = (float*)p;          p += (size_t)N_TOK * 4;
    unsigned short* W1t    = (unsigned short*)p; p += (size_t)HIDN * DIM * 2;
    unsigned short* W2t    = (unsigned short*)p; p += (size_t)HIDN * HIDN * 2;
    unsigned short* Wvut   = (unsigned short*)p; p += (size_t)HIDN * HIDN * 2;
    float*          bvu    = (float*)p;          p += 256 * 4;
    float*          Zp     = (float*)p;          p += (size_t)NSEG * 8 * HIDN * 4;

    dim3 tb(32, 8);
    transpose_cvt<<<dim3(HIDN / 32, DIM / 32), tb, 0, stream>>>(W1, W1t, DIM, HIDN);
    transpose_cvt<<<dim3(HIDN / 32, HIDN / 32), tb, 0, stream>>>(W2, W2t, HIDN, HIDN);
    transpose_cvt<<<dim3(ATTN / 32, HIDN / 32), tb, 0, stream>>>(Wv, Wvut, HIDN, ATTN);
    transpose_cvt<<<dim3(ATTN / 32, HIDN / 32), tb, 0, stream>>>(Wu, Wvut + (size_t)ATTN * HIDN, HIDN, ATTN);
    build_bvu<<<1, 256, 0, stream>>>(bv, bu, bvu);

    // gemm1 + LN + GELU -> h1b (bf16)
    gemm_fused<DIM, 0, true><<<N_TOK / 64, 256, 0, stream>>>(
        x, W1t, b1, g1, be1, h1b, nullptr, nullptr, nullptr);
    // gemm2 + LN + GELU -> h2b (bf16)
    gemm_fused<HIDN, 0, false><<<N_TOK / 64, 256, 0, stream>>>(
        h1b, W2t, b2, g2, be2, h2b, nullptr, nullptr, nullptr);
    // gemm3 (v|u) + tanh*sigmoid*Ww row-reduce -> scores (fp32)
    gemm_fused<HIDN, 1, false><<<N_TOK / 64, 256, 0, stream>>>(
        h2b, Wvut, bvu, nullptr, nullptr, nullptr, Ww, bw, scores);

    seg_softmax<<<NSEG, 256, 0, stream>>>(scores);
    pool_partial<<<NSEG * 8, 256, 0, stream>>>(scores, h2b, Zp);
    head_kernel<<<NSEG, 256, 0, stream>>>(Zp, Wc1, bc1, Wc2, bc2, out);
}